// Round 3
// baseline (872.889 us; speedup 1.0000x reference)
//
#include <hip/hip_runtime.h>
#include <cstdint>

typedef unsigned short u16;
typedef __attribute__((ext_vector_type(8))) __bf16 bf16x8;
typedef __attribute__((ext_vector_type(4))) float f32x4;

__device__ __forceinline__ u16 f2bf(float f) {
    union { float f; uint32_t u; } v; v.f = f;
    uint32_t u = v.u;
    uint32_t r = (u + 0x7fffu + ((u >> 16) & 1u)) >> 16;
    return (u16)r;
}
__device__ __forceinline__ float bf2f(u16 h) {
    union { uint32_t u; float f; } v; v.u = ((uint32_t)h) << 16;
    return v.f;
}

// async global->LDS 16B per lane; LDS dest must be wave-uniform base + lane*16
__device__ __forceinline__ void ld_lds16(const u16* g, u16* l) {
    __builtin_amdgcn_global_load_lds(
        (const __attribute__((address_space(1))) uint32_t*)g,
        (__attribute__((address_space(3))) uint32_t*)l, 16, 0, 0);
}

// ---------------------------------------------------------------- prep ------
__global__ __launch_bounds__(256) void prep(
    const float* __restrict__ proj_w, const float* __restrict__ proj_g,
    const float* __restrict__ proj_b, const float* __restrict__ vp2_w,
    const float* __restrict__ pw1_w, const float* __restrict__ pw2_w,
    const float* __restrict__ dw_w,
    u16* __restrict__ w1p, u16* __restrict__ w2, u16* __restrict__ w3,
    u16* __restrict__ w4, float* __restrict__ gp, float2* __restrict__ dwp)
{
    int i = blockIdx.x * 256 + threadIdx.x;
    if (i < 245760) {                 // w1p: 640x384, rows >=576 zero
        int o = i / 384, k = i - o * 384;
        w1p[i] = (o < 576) ? f2bf(proj_w[o * 386 + k]) : (u16)0;
        return;
    }
    i -= 245760;
    if (i < 73728) { w2[i] = f2bf(vp2_w[i]); return; }   // 384x192
    i -= 73728;
    if (i < 589824) { w3[i] = f2bf(pw1_w[i]); return; }  // 1536x384
    i -= 589824;
    if (i < 589824) { w4[i] = f2bf(pw2_w[i]); return; }  // 384x1536
    i -= 589824;
    if (i < 2560) {                   // gp: [g1p|b1p|w1x|w1y] each 640 fp32
        int which = i / 640, o = i - which * 640;
        float v = 0.f;
        if (o < 576) {
            v = (which == 0) ? proj_g[o] : (which == 1) ? proj_b[o]
                : (which == 2) ? proj_w[o * 386 + 384] : proj_w[o * 386 + 385];
        }
        gp[i] = v; return;
    }
    i -= 2560;
    if (i < 4800) {                   // dwp TRANSPOSED: [tap 0..24][cp 0..191]
        int tap = i / 192, cp = i - tap * 192;
        dwp[i] = make_float2(dw_w[(2 * cp) * 25 + tap], dw_w[(2 * cp + 1) * 25 + tap]);
    }
}

// ------------------------------------------------- NCHW fp32 -> NHWC bf16 ---
__global__ __launch_bounds__(256) void transpose_x(const float* __restrict__ x,
                                                   u16* __restrict__ xt)
{
    __shared__ float tile[64][65];
    int b = blockIdx.x, n0 = blockIdx.y * 64, c0 = blockIdx.z * 64;
    int t = threadIdx.x;
    int jj = t & 63, i0 = t >> 6;
    #pragma unroll
    for (int r = 0; r < 16; r++) {
        int ci = r * 4 + i0;
        tile[ci][jj] = x[((size_t)b * 384 + c0 + ci) * 4096 + n0 + jj];
    }
    __syncthreads();
    #pragma unroll
    for (int r = 0; r < 16; r++) {
        int ni = r * 4 + i0;
        xt[(size_t)(b * 4096 + n0 + ni) * 384 + c0 + jj] = f2bf(tile[jj][ni]);
    }
}

// ------------------------------------------------- NHWC bf16 -> NCHW fp32 ---
__global__ __launch_bounds__(256) void transpose_out(const u16* __restrict__ zf,
                                                     float* __restrict__ out)
{
    __shared__ float tile[64][65];
    int b = blockIdx.x, n0 = blockIdx.y * 64, c0 = blockIdx.z * 64;
    int t = threadIdx.x;
    int jj = t & 63, i0 = t >> 6;
    #pragma unroll
    for (int r = 0; r < 16; r++) {
        int ni = r * 4 + i0;
        tile[ni][jj] = bf2f(zf[(size_t)(b * 4096 + n0 + ni) * 384 + c0 + jj]);
    }
    __syncthreads();
    #pragma unroll
    for (int r = 0; r < 16; r++) {
        int ci = r * 4 + i0;
        out[((size_t)b * 384 + c0 + ci) * 4096 + n0 + jj] = tile[jj][ci];
    }
}

// --------------------------------------------------------------- GEMM -------
// Out[pix][o] = epilogue( sum_k A[pix][k] * W[o][k] )   (both k-contiguous)
// Grid: x = m-tile (512), y = o-tile  => linear id = m + 512*o, so the o-tiles
// sharing an A m-tile land on the same XCD (lin % 8 == m % 8) for L2 reuse.
// Staging: async global_load_lds width=16 (lane-contiguous LDS layout).
template <int MODE>
__global__ __launch_bounds__(256) void gemm_nhwc(
    const u16* __restrict__ A, const u16* __restrict__ W,
    u16* __restrict__ out, int K, int Osz,
    const float* __restrict__ g, const float* __restrict__ bb,
    const float* __restrict__ w1x, const float* __restrict__ w1y,
    const u16* __restrict__ res, const float* __restrict__ sc,
    const float* __restrict__ rnd)
{
    constexpr int BK = 32;
    __shared__ u16 sA[128 * BK];
    __shared__ u16 sB[128 * BK];
    const int tid = threadIdx.x;
    const int lane = tid & 63;
    const int wv = tid >> 6;
    const int wm = (wv >> 1) * 64;
    const int wn = (wv & 1) * 64;
    const int m0 = blockIdx.x * 128;
    const int o0 = blockIdx.y * 128;
    const int q = lane >> 4;
    const int mr = lane & 15;

    const size_t arow  = (size_t)(m0 + (tid >> 2)) * K + (tid & 3) * 8;
    const size_t arow2 = (size_t)(m0 + 64 + (tid >> 2)) * K + (tid & 3) * 8;
    const size_t wrow  = (size_t)(o0 + (tid >> 2)) * K + (tid & 3) * 8;
    const size_t wrow2 = (size_t)(o0 + 64 + (tid >> 2)) * K + (tid & 3) * 8;

    f32x4 acc[4][4] = {};

    for (int k0 = 0; k0 < K; k0 += BK) {
        __syncthreads();
        ld_lds16(A + arow + k0, sA + (size_t)tid * 8);
        ld_lds16(A + arow2 + k0, sA + (size_t)(tid + 256) * 8);
        ld_lds16(W + wrow + k0, sB + (size_t)tid * 8);
        ld_lds16(W + wrow2 + k0, sB + (size_t)(tid + 256) * 8);
        __syncthreads();
        bf16x8 af[4], bf[4];
        #pragma unroll
        for (int i = 0; i < 4; i++)
            af[i] = *(const bf16x8*)&sA[(wm + i * 16 + mr) * BK + q * 8];
        #pragma unroll
        for (int j = 0; j < 4; j++)
            bf[j] = *(const bf16x8*)&sB[(wn + j * 16 + mr) * BK + q * 8];
        #pragma unroll
        for (int i = 0; i < 4; i++)
            #pragma unroll
            for (int j = 0; j < 4; j++)
                acc[i][j] = __builtin_amdgcn_mfma_f32_16x16x32_bf16(af[i], bf[j], acc[i][j], 0, 0, 0);
    }

    float E = 0.f, offx = 0.f, offy = 0.f, rz = 0.f;
    if constexpr (MODE == 1) {
        E = expf(sc[0]);
        int bimg = m0 >> 12;
        offx = rnd[bimg * 2 + 0];
        offy = rnd[bimg * 2 + 1];
    }
    if constexpr (MODE == 2 || MODE == 4) rz = sc[0];

    #pragma unroll
    for (int j = 0; j < 4; j++) {
        int o = o0 + wn + j * 16 + mr;
        float gg = g[o], bbv = bb[o];
        float wx = 0.f, wy = 0.f;
        if constexpr (MODE == 1) { wx = w1x[o]; wy = w1y[o]; }
        #pragma unroll
        for (int i = 0; i < 4; i++) {
            #pragma unroll
            for (int r = 0; r < 4; r++) {
                int pix = m0 + wm + i * 16 + q * 4 + r;
                float v = acc[i][j][r];
                if constexpr (MODE == 1) {
                    int n = pix & 4095;
                    float px = E * ((float)(n & 63) * 0.001f + offx);
                    float py = E * ((float)(n >> 6) * 0.001f + offy);
                    v += px * wx + py * wy;
                    v = fmaxf(gg * v + bbv, 0.f);
                } else if constexpr (MODE == 2) {
                    v = fmaxf(gg * v + bbv, 0.f);
                    v = bf2f(res[(size_t)pix * 384 + o]) + rz * v;
                } else if constexpr (MODE == 3) {
                    float t = gg * v + bbv;
                    v = t * fminf(fmaxf(t + 3.f, 0.f), 6.f) * (1.f / 6.f);
                } else {
                    float t = gg * v + bbv;
                    v = bf2f(res[(size_t)pix * 384 + o]) + rz * t;
                }
                out[(size_t)pix * Osz + o] = f2bf(v);
            }
        }
    }
}

// ----------------------------------------------------------- attention ------
__global__ __launch_bounds__(256) void attn_ktv(const u16* __restrict__ proj,
                                                float* __restrict__ ktv)
{
    int bh = blockIdx.x;
    int b = bh / 12, h = bh - b * 12;
    const u16* base = proj + (size_t)b * 4096 * 640;
    int kc = 192 + h * 16, vc = 384 + h * 16;
    __shared__ u16 ks[256 * 16];
    __shared__ u16 vs[256 * 16];
    int t = threadIdx.x;
    int d = t >> 4, e = t & 15;
    float acc = 0.f, ksum = 0.f;
    for (int n0 = 0; n0 < 4096; n0 += 256) {
        __syncthreads();
        const u16* r = base + (size_t)(n0 + t) * 640;
        ((float4*)&ks[t * 16])[0] = ((const float4*)(r + kc))[0];
        ((float4*)&ks[t * 16])[1] = ((const float4*)(r + kc))[1];
        ((float4*)&vs[t * 16])[0] = ((const float4*)(r + vc))[0];
        ((float4*)&vs[t * 16])[1] = ((const float4*)(r + vc))[1];
        __syncthreads();
        #pragma unroll 8
        for (int n = 0; n < 256; n++)
            acc += bf2f(ks[n * 16 + d]) * bf2f(vs[n * 16 + e]);
        if (t < 16) {
            #pragma unroll 8
            for (int n = 0; n < 256; n++) ksum += bf2f(ks[n * 16 + t]);
        }
    }
    ktv[(size_t)bh * 272 + t] = acc;
    if (t < 16) ktv[(size_t)bh * 272 + 256 + t] = ksum;
}

__global__ __launch_bounds__(256) void attn_apply(const u16* __restrict__ proj,
                                                  const float* __restrict__ ktv,
                                                  u16* __restrict__ att)
{
    int bh = blockIdx.x;
    int b = bh / 12, h = bh - b * 12;
    __shared__ float kt[272];
    int t = threadIdx.x;
    kt[t] = ktv[(size_t)bh * 272 + t];
    if (t < 16) kt[256 + t] = ktv[(size_t)bh * 272 + 256 + t];
    __syncthreads();
    int n = blockIdx.y * 256 + t;
    const u16* qr = proj + (size_t)(b * 4096 + n) * 640 + h * 16;
    float qv[16];
    #pragma unroll
    for (int d = 0; d < 16; d++) qv[d] = bf2f(qr[d]);
    float denom = 0.f;
    #pragma unroll
    for (int d = 0; d < 16; d++) denom += qv[d] * kt[256 + d];
    float rcp = 1.f / fmaxf(denom, 1e-4f);
    u16* op = att + (size_t)(b * 4096 + n) * 192 + h * 16;
    #pragma unroll
    for (int e = 0; e < 16; e++) {
        float s = 0.f;
        #pragma unroll
        for (int d = 0; d < 16; d++) s += qv[d] * kt[d * 16 + e];
        op[e] = f2bf(s * rcp);
    }
}

// -------------------------------------------------------- depthwise 5x5 -----
__global__ __launch_bounds__(192) void dwconv(const u16* __restrict__ y,
                                              const float2* __restrict__ wt,
                                              const float* __restrict__ g,
                                              const float* __restrict__ bc,
                                              u16* __restrict__ z)
{
    const int cp = threadIdx.x;        // 0..191
    const int xc = blockIdx.x;         // 0..63
    const int b  = blockIdx.y;         // 0..15
    const int c0 = cp * 2;

    float2 wv[25];
    #pragma unroll
    for (int t = 0; t < 25; t++) wv[t] = wt[t * 192 + cp];
    const float g0 = g[c0], g1 = g[c0 + 1];
    const float b0 = bc[c0], b1 = bc[c0 + 1];

    const size_t ibase = (size_t)b * 4096;
    const u16* ycol = y + ibase * 384 + c0;

    uint32_t r0[5], r1[5], r2[5], r3[5], r4[5];

#define LOADROW(yy, dst)                                                     \
    {                                                                        \
        if ((unsigned)(yy) < 64u) {                                          \
            const u16* rp = ycol + (size_t)(yy) * 64 * 384;                  \
            _Pragma("unroll")                                                \
            for (int dx = 0; dx < 5; dx++) {                                 \
                int xx = xc + dx - 2;                                        \
                dst[dx] = ((unsigned)xx < 64u)                               \
                              ? *(const uint32_t*)(rp + (size_t)xx * 384)    \
                              : 0u;                                          \
            }                                                                \
        } else {                                                             \
            _Pragma("unroll")                                                \
            for (int dx = 0; dx < 5; dx++) dst[dx] = 0u;                     \
        }                                                                    \
    }

#define COMPUTE(yr, A, B, C, D, E)                                           \
    if ((yr) < 64) {                                                         \
        float a0 = 0.f, a1 = 0.f;                                            \
        _Pragma("unroll")                                                    \
        for (int dx = 0; dx < 5; dx++) {                                     \
            uint32_t p;                                                      \
            p = A[dx];                                                       \
            a0 += wv[dx].x * bf2f((u16)(p & 0xffffu));                       \
            a1 += wv[dx].y * bf2f((u16)(p >> 16));                           \
            p = B[dx];                                                       \
            a0 += wv[5 + dx].x * bf2f((u16)(p & 0xffffu));                   \
            a1 += wv[5 + dx].y * bf2f((u16)(p >> 16));                       \
            p = C[dx];                                                       \
            a0 += wv[10 + dx].x * bf2f((u16)(p & 0xffffu));                  \
            a1 += wv[10 + dx].y * bf2f((u16)(p >> 16));                      \
            p = D[dx];                                                       \
            a0 += wv[15 + dx].x * bf2f((u16)(p & 0xffffu));                  \
            a1 += wv[15 + dx].y * bf2f((u16)(p >> 16));                      \
            p = E[dx];                                                       \
            a0 += wv[20 + dx].x * bf2f((u16)(p & 0xffffu));                  \
            a1 += wv[20 + dx].y * bf2f((u16)(p >> 16));                      \
        }                                                                    \
        float t0 = g0 * a0 + b0;                                             \
        float t1 = g1 * a1 + b1;                                             \
        t0 = t0 * fminf(fmaxf(t0 + 3.f, 0.f), 6.f) * (1.f / 6.f);            \
        t1 = t1 * fminf(fmaxf(t1 + 3.f, 0.f), 6.f) * (1.f / 6.f);            \
        uint32_t packed = (uint32_t)f2bf(t0) | ((uint32_t)f2bf(t1) << 16);   \
        *(uint32_t*)(z + (ibase + (size_t)(yr) * 64 + xc) * 384 + c0) = packed; \
    }

#define STEP(yr, A, B, C, D, E)                                              \
    COMPUTE(yr, A, B, C, D, E)                                               \
    LOADROW((yr) + 3, A)

    LOADROW(-2, r0)
    LOADROW(-1, r1)
    LOADROW(0, r2)
    LOADROW(1, r3)
    LOADROW(2, r4)

    for (int base = 0; base < 65; base += 5) {
        STEP(base + 0, r0, r1, r2, r3, r4)
        STEP(base + 1, r1, r2, r3, r4, r0)
        STEP(base + 2, r2, r3, r4, r0, r1)
        STEP(base + 3, r3, r4, r0, r1, r2)
        STEP(base + 4, r4, r0, r1, r2, r3)
    }
#undef STEP
#undef COMPUTE
#undef LOADROW
}

// ---------------------------------------------------------------------------
extern "C" void kernel_launch(void* const* d_in, const int* in_sizes, int n_in,
                              void* d_out, int out_size, void* d_ws, size_t ws_size,
                              hipStream_t stream)
{
    (void)in_sizes; (void)n_in; (void)out_size; (void)ws_size;
    const float* x       = (const float*)d_in[0];
    const float* rnd     = (const float*)d_in[1];
    const float* proj_w  = (const float*)d_in[2];
    const float* proj_g  = (const float*)d_in[3];
    const float* proj_b  = (const float*)d_in[4];
    const float* vp2_w   = (const float*)d_in[5];
    const float* vp2_g   = (const float*)d_in[6];
    const float* vp2_b   = (const float*)d_in[7];
    const float* dw_w    = (const float*)d_in[8];
    const float* dw_g    = (const float*)d_in[9];
    const float* dw_b    = (const float*)d_in[10];
    const float* pw1_w   = (const float*)d_in[11];
    const float* pw1_g   = (const float*)d_in[12];
    const float* pw1_b   = (const float*)d_in[13];
    const float* pw2_w   = (const float*)d_in[14];
    const float* out_g   = (const float*)d_in[15];
    const float* out_b   = (const float*)d_in[16];
    const float* rz_attn = (const float*)d_in[17];
    const float* rz_ffn  = (const float*)d_in[18];
    const float* es      = (const float*)d_in[19];
    float* out = (float*)d_out;

    char* ws = (char*)d_ws;
    u16*   xt   = (u16*)(ws + 0);            // 65536x384 bf16 (z2 aliases from 0)
    u16*   att  = (u16*)(ws + 50331648);     // 65536x192 bf16
    u16*   z2   = (u16*)(ws + 0);            // 65536x1536 bf16 (xt+att dead by then)
    u16*   proj = (u16*)(ws + 201326592);    // 65536x640 bf16
    u16*   z1   = proj;                      // 65536x384 (proj dead)
    u16*   z4   = proj;                      // 65536x384 (z1 dead)
    u16*   yt   = (u16*)(ws + 285212672);    // 65536x384 bf16
    float* ktv  = (float*)(ws + 335544320);  // 192x272 fp32
    u16*   w1p  = (u16*)(ws + 335753216);    // 640x384 bf16
    u16*   w2   = (u16*)(ws + 336244736);    // 384x192
    u16*   w3   = (u16*)(ws + 336392192);    // 1536x384
    u16*   w4   = (u16*)(ws + 337571840);    // 384x1536
    float* gp   = (float*)(ws + 338751488);  // 4x640 fp32
    float2* dwp = (float2*)(ws + 338761728); // 25x192 float2 (transposed)

    prep<<<5885, 256, 0, stream>>>(proj_w, proj_g, proj_b, vp2_w, pw1_w, pw2_w,
                                   dw_w, w1p, w2, w3, w4, gp, dwp);
    transpose_x<<<dim3(16, 64, 6), 256, 0, stream>>>(x, xt);
    gemm_nhwc<1><<<dim3(512, 5), 256, 0, stream>>>(xt, w1p, proj, 384, 640,
        gp, gp + 640, gp + 1280, gp + 1920, nullptr, es, rnd);
    attn_ktv<<<192, 256, 0, stream>>>(proj, ktv);
    attn_apply<<<dim3(192, 16), 256, 0, stream>>>(proj, ktv, att);
    gemm_nhwc<2><<<dim3(512, 3), 256, 0, stream>>>(att, w2, yt, 192, 384,
        vp2_g, vp2_b, nullptr, nullptr, xt, rz_attn, nullptr);
    dwconv<<<dim3(64, 16), 192, 0, stream>>>(yt, dwp, dw_g, dw_b, z1);
    gemm_nhwc<3><<<dim3(512, 12), 256, 0, stream>>>(z1, w3, z2, 384, 1536,
        pw1_g, pw1_b, nullptr, nullptr, nullptr, nullptr, nullptr);
    gemm_nhwc<4><<<dim3(512, 3), 256, 0, stream>>>(z2, w4, z4, 1536, 384,
        out_g, out_b, nullptr, nullptr, yt, rz_ffn, nullptr);
    transpose_out<<<dim3(16, 64, 6), 256, 0, stream>>>(z4, out);
}

// Round 4
// 773.649 us; speedup vs baseline: 1.1283x; 1.1283x over previous
//
#include <hip/hip_runtime.h>
#include <cstdint>

typedef unsigned short u16;
typedef __attribute__((ext_vector_type(8))) __bf16 bf16x8;
typedef __attribute__((ext_vector_type(4))) float f32x4;

__device__ __forceinline__ u16 f2bf(float f) {
    union { float f; uint32_t u; } v; v.f = f;
    uint32_t u = v.u;
    uint32_t r = (u + 0x7fffu + ((u >> 16) & 1u)) >> 16;
    return (u16)r;
}
__device__ __forceinline__ float bf2f(u16 h) {
    union { uint32_t u; float f; } v; v.u = ((uint32_t)h) << 16;
    return v.f;
}

// async global->LDS 16B per lane; LDS dest must be wave-uniform base + lane*16
__device__ __forceinline__ void ld_lds16(const u16* g, u16* l) {
    __builtin_amdgcn_global_load_lds(
        (const __attribute__((address_space(1))) uint32_t*)g,
        (__attribute__((address_space(3))) uint32_t*)l, 16, 0, 0);
}

// ---------------------------------------------------------------- prep ------
__global__ __launch_bounds__(256) void prep(
    const float* __restrict__ proj_w, const float* __restrict__ proj_g,
    const float* __restrict__ proj_b, const float* __restrict__ vp2_w,
    const float* __restrict__ pw1_w, const float* __restrict__ pw2_w,
    const float* __restrict__ dw_w,
    u16* __restrict__ w1p, u16* __restrict__ w2, u16* __restrict__ w3,
    u16* __restrict__ w4, float* __restrict__ gp, float2* __restrict__ dwp)
{
    int i = blockIdx.x * 256 + threadIdx.x;
    if (i < 245760) {                 // w1p: 640x384, rows >=576 zero
        int o = i / 384, k = i - o * 384;
        w1p[i] = (o < 576) ? f2bf(proj_w[o * 386 + k]) : (u16)0;
        return;
    }
    i -= 245760;
    if (i < 73728) { w2[i] = f2bf(vp2_w[i]); return; }   // 384x192
    i -= 73728;
    if (i < 589824) { w3[i] = f2bf(pw1_w[i]); return; }  // 1536x384
    i -= 589824;
    if (i < 589824) { w4[i] = f2bf(pw2_w[i]); return; }  // 384x1536
    i -= 589824;
    if (i < 2560) {                   // gp: [g1p|b1p|w1x|w1y] each 640 fp32
        int which = i / 640, o = i - which * 640;
        float v = 0.f;
        if (o < 576) {
            v = (which == 0) ? proj_g[o] : (which == 1) ? proj_b[o]
                : (which == 2) ? proj_w[o * 386 + 384] : proj_w[o * 386 + 385];
        }
        gp[i] = v; return;
    }
    i -= 2560;
    if (i < 4800) {                   // dwp TRANSPOSED: [tap 0..24][cp 0..191]
        int tap = i / 192, cp = i - tap * 192;
        dwp[i] = make_float2(dw_w[(2 * cp) * 25 + tap], dw_w[(2 * cp + 1) * 25 + tap]);
    }
}

// ------------------------------------------------- NCHW fp32 -> NHWC bf16 ---
__global__ __launch_bounds__(256) void transpose_x(const float* __restrict__ x,
                                                   u16* __restrict__ xt)
{
    __shared__ float tile[64][65];
    int b = blockIdx.x, n0 = blockIdx.y * 64, c0 = blockIdx.z * 64;
    int t = threadIdx.x;
    int jj = t & 63, i0 = t >> 6;
    #pragma unroll
    for (int r = 0; r < 16; r++) {
        int ci = r * 4 + i0;
        tile[ci][jj] = x[((size_t)b * 384 + c0 + ci) * 4096 + n0 + jj];
    }
    __syncthreads();
    #pragma unroll
    for (int r = 0; r < 16; r++) {
        int ni = r * 4 + i0;
        xt[(size_t)(b * 4096 + n0 + ni) * 384 + c0 + jj] = f2bf(tile[jj][ni]);
    }
}

// ------------------------------------------------- NHWC bf16 -> NCHW fp32 ---
__global__ __launch_bounds__(256) void transpose_out(const u16* __restrict__ zf,
                                                     float* __restrict__ out)
{
    __shared__ float tile[64][65];
    int b = blockIdx.x, n0 = blockIdx.y * 64, c0 = blockIdx.z * 64;
    int t = threadIdx.x;
    int jj = t & 63, i0 = t >> 6;
    #pragma unroll
    for (int r = 0; r < 16; r++) {
        int ni = r * 4 + i0;
        tile[ni][jj] = bf2f(zf[(size_t)(b * 4096 + n0 + ni) * 384 + c0 + jj]);
    }
    __syncthreads();
    #pragma unroll
    for (int r = 0; r < 16; r++) {
        int ci = r * 4 + i0;
        out[((size_t)b * 384 + c0 + ci) * 4096 + n0 + jj] = tile[jj][ci];
    }
}

// --------------------------------------------------------------- GEMM -------
// Out[pix][o] = epilogue( sum_k A[pix][k] * W[o][k] )   (both k-contiguous)
// Double-buffered LDS + async global_load_lds: one barrier per K-iter;
// the DMA for tile k+1 is issued right after the barrier and lands during
// tile k's MFMA phase (overlap). Grid: x = m-tile (XCD affinity), y = o-tile.
template <int MODE>
__global__ __launch_bounds__(256) void gemm_nhwc(
    const u16* __restrict__ A, const u16* __restrict__ W,
    u16* __restrict__ out, int K, int Osz,
    const float* __restrict__ g, const float* __restrict__ bb,
    const float* __restrict__ w1x, const float* __restrict__ w1y,
    const u16* __restrict__ res, const float* __restrict__ sc,
    const float* __restrict__ rnd)
{
    constexpr int BK = 32;
    __shared__ u16 sA[2][128 * BK];
    __shared__ u16 sB[2][128 * BK];
    const int tid = threadIdx.x;
    const int lane = tid & 63;
    const int wv = tid >> 6;
    const int wm = (wv >> 1) * 64;
    const int wn = (wv & 1) * 64;
    const int m0 = blockIdx.x * 128;
    const int o0 = blockIdx.y * 128;
    const int q = lane >> 4;
    const int mr = lane & 15;

    const int tq = tid >> 2;          // staging row 0..63 (+64 for 2nd group)
    const int tk = (tid & 3) * 8;     // staging k-offset (elements)
    const size_t ga0 = (size_t)(m0 + tq) * K + tk;
    const size_t ga1 = (size_t)(m0 + 64 + tq) * K + tk;
    const size_t gb0 = (size_t)(o0 + tq) * K + tk;
    const size_t gb1 = (size_t)(o0 + 64 + tq) * K + tk;
    const int lo0 = tq * BK + tk;
    const int lo1 = (64 + tq) * BK + tk;

    f32x4 acc[4][4] = {};

    ld_lds16(A + ga0, &sA[0][lo0]);
    ld_lds16(A + ga1, &sA[0][lo1]);
    ld_lds16(W + gb0, &sB[0][lo0]);
    ld_lds16(W + gb1, &sB[0][lo1]);

    int buf = 0;
    for (int k0 = 0; k0 < K; k0 += BK) {
        __syncthreads();              // drains DMA for 'buf'
        if (k0 + BK < K) {            // prefetch next tile into other buffer
            ld_lds16(A + ga0 + k0 + BK, &sA[buf ^ 1][lo0]);
            ld_lds16(A + ga1 + k0 + BK, &sA[buf ^ 1][lo1]);
            ld_lds16(W + gb0 + k0 + BK, &sB[buf ^ 1][lo0]);
            ld_lds16(W + gb1 + k0 + BK, &sB[buf ^ 1][lo1]);
        }
        bf16x8 af[4], bfr[4];
        #pragma unroll
        for (int i = 0; i < 4; i++)
            af[i] = *(const bf16x8*)&sA[buf][(wm + i * 16 + mr) * BK + q * 8];
        #pragma unroll
        for (int j = 0; j < 4; j++)
            bfr[j] = *(const bf16x8*)&sB[buf][(wn + j * 16 + mr) * BK + q * 8];
        #pragma unroll
        for (int i = 0; i < 4; i++)
            #pragma unroll
            for (int j = 0; j < 4; j++)
                acc[i][j] = __builtin_amdgcn_mfma_f32_16x16x32_bf16(af[i], bfr[j], acc[i][j], 0, 0, 0);
        buf ^= 1;
    }

    float E = 0.f, offx = 0.f, offy = 0.f, rz = 0.f;
    if constexpr (MODE == 1) {
        E = expf(sc[0]);
        int bimg = m0 >> 12;
        offx = rnd[bimg * 2 + 0];
        offy = rnd[bimg * 2 + 1];
    }
    if constexpr (MODE == 2 || MODE == 4) rz = sc[0];

    #pragma unroll
    for (int j = 0; j < 4; j++) {
        int o = o0 + wn + j * 16 + mr;
        float gg = g[o], bbv = bb[o];
        float wx = 0.f, wy = 0.f;
        if constexpr (MODE == 1) { wx = w1x[o]; wy = w1y[o]; }
        #pragma unroll
        for (int i = 0; i < 4; i++) {
            #pragma unroll
            for (int r = 0; r < 4; r++) {
                int pix = m0 + wm + i * 16 + q * 4 + r;
                float v = acc[i][j][r];
                if constexpr (MODE == 1) {
                    int n = pix & 4095;
                    float px = E * ((float)(n & 63) * 0.001f + offx);
                    float py = E * ((float)(n >> 6) * 0.001f + offy);
                    v += px * wx + py * wy;
                    v = fmaxf(gg * v + bbv, 0.f);
                } else if constexpr (MODE == 2) {
                    v = fmaxf(gg * v + bbv, 0.f);
                    v = bf2f(res[(size_t)pix * 384 + o]) + rz * v;
                } else if constexpr (MODE == 3) {
                    float t = gg * v + bbv;
                    v = t * fminf(fmaxf(t + 3.f, 0.f), 6.f) * (1.f / 6.f);
                } else {
                    float t = gg * v + bbv;
                    v = bf2f(res[(size_t)pix * 384 + o]) + rz * t;
                }
                out[(size_t)pix * Osz + o] = f2bf(v);
            }
        }
    }
}

// ----------------------------------------------------------- attention ------
// Partial ktv over 4 N-chunks (768 blocks instead of 192 for occupancy);
// attn_apply sums the partials.
__global__ __launch_bounds__(256) void attn_ktv(const u16* __restrict__ proj,
                                                float* __restrict__ ktvp)
{
    int bh = blockIdx.x;
    int ch = blockIdx.y;
    int b = bh / 12, h = bh - b * 12;
    const u16* base = proj + (size_t)b * 4096 * 640;
    int kc = 192 + h * 16, vc = 384 + h * 16;
    __shared__ u16 ks[256 * 16];
    __shared__ u16 vs[256 * 16];
    int t = threadIdx.x;
    int d = t >> 4, e = t & 15;
    float acc = 0.f, ksum = 0.f;
    for (int n0 = ch * 1024; n0 < ch * 1024 + 1024; n0 += 256) {
        __syncthreads();
        const u16* r = base + (size_t)(n0 + t) * 640;
        ((float4*)&ks[t * 16])[0] = ((const float4*)(r + kc))[0];
        ((float4*)&ks[t * 16])[1] = ((const float4*)(r + kc))[1];
        ((float4*)&vs[t * 16])[0] = ((const float4*)(r + vc))[0];
        ((float4*)&vs[t * 16])[1] = ((const float4*)(r + vc))[1];
        __syncthreads();
        #pragma unroll 8
        for (int n = 0; n < 256; n++)
            acc += bf2f(ks[n * 16 + d]) * bf2f(vs[n * 16 + e]);
        if (t < 16) {
            #pragma unroll 8
            for (int n = 0; n < 256; n++) ksum += bf2f(ks[n * 16 + t]);
        }
    }
    float* o = ktvp + ((size_t)bh * 4 + ch) * 272;
    o[t] = acc;
    if (t < 16) o[256 + t] = ksum;
}

__global__ __launch_bounds__(256) void attn_apply(const u16* __restrict__ proj,
                                                  const float* __restrict__ ktvp,
                                                  u16* __restrict__ att)
{
    int bh = blockIdx.x;
    int b = bh / 12, h = bh - b * 12;
    __shared__ float kt[272];
    int t = threadIdx.x;
    {
        const float* p = ktvp + (size_t)bh * 4 * 272;
        kt[t] = p[t] + p[272 + t] + p[544 + t] + p[816 + t];
        if (t < 16) {
            int u = 256 + t;
            kt[u] = p[u] + p[272 + u] + p[544 + u] + p[816 + u];
        }
    }
    __syncthreads();
    int n = blockIdx.y * 256 + t;
    const u16* qr = proj + (size_t)(b * 4096 + n) * 640 + h * 16;
    float qv[16];
    #pragma unroll
    for (int d = 0; d < 16; d++) qv[d] = bf2f(qr[d]);
    float denom = 0.f;
    #pragma unroll
    for (int d = 0; d < 16; d++) denom += qv[d] * kt[256 + d];
    float rcp = 1.f / fmaxf(denom, 1e-4f);
    u16* op = att + (size_t)(b * 4096 + n) * 192 + h * 16;
    #pragma unroll
    for (int e = 0; e < 16; e++) {
        float s = 0.f;
        #pragma unroll
        for (int d = 0; d < 16; d++) s += qv[d] * kt[d * 16 + e];
        op[e] = f2bf(s * rcp);
    }
}

// -------------------------------------------------------- depthwise 5x5 -----
__global__ __launch_bounds__(192) void dwconv(const u16* __restrict__ y,
                                              const float2* __restrict__ wt,
                                              const float* __restrict__ g,
                                              const float* __restrict__ bc,
                                              u16* __restrict__ z)
{
    const int cp = threadIdx.x;        // 0..191
    const int xc = blockIdx.x;         // 0..63
    const int b  = blockIdx.y;         // 0..15
    const int c0 = cp * 2;

    float2 wv[25];
    #pragma unroll
    for (int t = 0; t < 25; t++) wv[t] = wt[t * 192 + cp];
    const float g0 = g[c0], g1 = g[c0 + 1];
    const float b0 = bc[c0], b1 = bc[c0 + 1];

    const size_t ibase = (size_t)b * 4096;
    const u16* ycol = y + ibase * 384 + c0;

    uint32_t r0[5], r1[5], r2[5], r3[5], r4[5];

#define LOADROW(yy, dst)                                                     \
    {                                                                        \
        if ((unsigned)(yy) < 64u) {                                          \
            const u16* rp = ycol + (size_t)(yy) * 64 * 384;                  \
            _Pragma("unroll")                                                \
            for (int dx = 0; dx < 5; dx++) {                                 \
                int xx = xc + dx - 2;                                        \
                dst[dx] = ((unsigned)xx < 64u)                               \
                              ? *(const uint32_t*)(rp + (size_t)xx * 384)    \
                              : 0u;                                          \
            }                                                                \
        } else {                                                             \
            _Pragma("unroll")                                                \
            for (int dx = 0; dx < 5; dx++) dst[dx] = 0u;                     \
        }                                                                    \
    }

#define COMPUTE(yr, A, B, C, D, E)                                           \
    if ((yr) < 64) {                                                         \
        float a0 = 0.f, a1 = 0.f;                                            \
        _Pragma("unroll")                                                    \
        for (int dx = 0; dx < 5; dx++) {                                     \
            uint32_t p;                                                      \
            p = A[dx];                                                       \
            a0 += wv[dx].x * bf2f((u16)(p & 0xffffu));                       \
            a1 += wv[dx].y * bf2f((u16)(p >> 16));                           \
            p = B[dx];                                                       \
            a0 += wv[5 + dx].x * bf2f((u16)(p & 0xffffu));                   \
            a1 += wv[5 + dx].y * bf2f((u16)(p >> 16));                       \
            p = C[dx];                                                       \
            a0 += wv[10 + dx].x * bf2f((u16)(p & 0xffffu));                  \
            a1 += wv[10 + dx].y * bf2f((u16)(p >> 16));                      \
            p = D[dx];                                                       \
            a0 += wv[15 + dx].x * bf2f((u16)(p & 0xffffu));                  \
            a1 += wv[15 + dx].y * bf2f((u16)(p >> 16));                      \
            p = E[dx];                                                       \
            a0 += wv[20 + dx].x * bf2f((u16)(p & 0xffffu));                  \
            a1 += wv[20 + dx].y * bf2f((u16)(p >> 16));                      \
        }                                                                    \
        float t0 = g0 * a0 + b0;                                             \
        float t1 = g1 * a1 + b1;                                             \
        t0 = t0 * fminf(fmaxf(t0 + 3.f, 0.f), 6.f) * (1.f / 6.f);            \
        t1 = t1 * fminf(fmaxf(t1 + 3.f, 0.f), 6.f) * (1.f / 6.f);            \
        uint32_t packed = (uint32_t)f2bf(t0) | ((uint32_t)f2bf(t1) << 16);   \
        *(uint32_t*)(z + (ibase + (size_t)(yr) * 64 + xc) * 384 + c0) = packed; \
    }

#define STEP(yr, A, B, C, D, E)                                              \
    COMPUTE(yr, A, B, C, D, E)                                               \
    LOADROW((yr) + 3, A)

    LOADROW(-2, r0)
    LOADROW(-1, r1)
    LOADROW(0, r2)
    LOADROW(1, r3)
    LOADROW(2, r4)

    for (int base = 0; base < 65; base += 5) {
        STEP(base + 0, r0, r1, r2, r3, r4)
        STEP(base + 1, r1, r2, r3, r4, r0)
        STEP(base + 2, r2, r3, r4, r0, r1)
        STEP(base + 3, r3, r4, r0, r1, r2)
        STEP(base + 4, r4, r0, r1, r2, r3)
    }
#undef STEP
#undef COMPUTE
#undef LOADROW
}

// ---------------------------------------------------------------------------
extern "C" void kernel_launch(void* const* d_in, const int* in_sizes, int n_in,
                              void* d_out, int out_size, void* d_ws, size_t ws_size,
                              hipStream_t stream)
{
    (void)in_sizes; (void)n_in; (void)out_size; (void)ws_size;
    const float* x       = (const float*)d_in[0];
    const float* rnd     = (const float*)d_in[1];
    const float* proj_w  = (const float*)d_in[2];
    const float* proj_g  = (const float*)d_in[3];
    const float* proj_b  = (const float*)d_in[4];
    const float* vp2_w   = (const float*)d_in[5];
    const float* vp2_g   = (const float*)d_in[6];
    const float* vp2_b   = (const float*)d_in[7];
    const float* dw_w    = (const float*)d_in[8];
    const float* dw_g    = (const float*)d_in[9];
    const float* dw_b    = (const float*)d_in[10];
    const float* pw1_w   = (const float*)d_in[11];
    const float* pw1_g   = (const float*)d_in[12];
    const float* pw1_b   = (const float*)d_in[13];
    const float* pw2_w   = (const float*)d_in[14];
    const float* out_g   = (const float*)d_in[15];
    const float* out_b   = (const float*)d_in[16];
    const float* rz_attn = (const float*)d_in[17];
    const float* rz_ffn  = (const float*)d_in[18];
    const float* es      = (const float*)d_in[19];
    float* out = (float*)d_out;

    char* ws = (char*)d_ws;
    u16*   xt   = (u16*)(ws + 0);            // 65536x384 bf16 (z2 aliases from 0)
    u16*   att  = (u16*)(ws + 50331648);     // 65536x192 bf16
    u16*   z2   = (u16*)(ws + 0);            // 65536x1536 bf16 (xt+att dead by then)
    u16*   proj = (u16*)(ws + 201326592);    // 65536x640 bf16
    u16*   z1   = proj;                      // 65536x384 (proj dead)
    u16*   z4   = proj;                      // 65536x384 (z1 dead)
    u16*   yt   = (u16*)(ws + 285212672);    // 65536x384 bf16
    u16*   w1p  = (u16*)(ws + 335753216);    // 640x384 bf16
    u16*   w2   = (u16*)(ws + 336244736);    // 384x192
    u16*   w3   = (u16*)(ws + 336392192);    // 1536x384
    u16*   w4   = (u16*)(ws + 337571840);    // 384x1536
    float* gp   = (float*)(ws + 338751488);  // 4x640 fp32
    float2* dwp = (float2*)(ws + 338761728); // 25x192 float2 (transposed)
    float* ktvp = (float*)(ws + 338800128);  // 192x4x272 fp32 partials

    prep<<<5885, 256, 0, stream>>>(proj_w, proj_g, proj_b, vp2_w, pw1_w, pw2_w,
                                   dw_w, w1p, w2, w3, w4, gp, dwp);
    transpose_x<<<dim3(16, 64, 6), 256, 0, stream>>>(x, xt);
    gemm_nhwc<1><<<dim3(512, 5), 256, 0, stream>>>(xt, w1p, proj, 384, 640,
        gp, gp + 640, gp + 1280, gp + 1920, nullptr, es, rnd);
    attn_ktv<<<dim3(192, 4), 256, 0, stream>>>(proj, ktvp);
    attn_apply<<<dim3(192, 16), 256, 0, stream>>>(proj, ktvp, att);
    gemm_nhwc<2><<<dim3(512, 3), 256, 0, stream>>>(att, w2, yt, 192, 384,
        vp2_g, vp2_b, nullptr, nullptr, xt, rz_attn, nullptr);
    dwconv<<<dim3(64, 16), 192, 0, stream>>>(yt, dwp, dw_g, dw_b, z1);
    gemm_nhwc<3><<<dim3(512, 12), 256, 0, stream>>>(z1, w3, z2, 384, 1536,
        pw1_g, pw1_b, nullptr, nullptr, nullptr, nullptr, nullptr);
    gemm_nhwc<4><<<dim3(512, 3), 256, 0, stream>>>(z2, w4, z4, 1536, 384,
        out_g, out_b, nullptr, nullptr, yt, rz_ffn, nullptr);
    transpose_out<<<dim3(16, 64, 6), 256, 0, stream>>>(z4, out);
}